// Round 1
// baseline (904.776 us; speedup 1.0000x reference)
//
#include <hip/hip_runtime.h>

typedef __attribute__((ext_vector_type(4))) float f32x4;
typedef __attribute__((ext_vector_type(8))) __bf16 bf16x8;
typedef __attribute__((ext_vector_type(4))) unsigned short u16x4;

#define DEVI static __device__ __forceinline__

static constexpr int S_LEN = 2048;
static constexpr int HID   = 4096;
static constexpr int NH    = 32;
static constexpr int NKV   = 8;
static constexpr int HD    = 128;

DEVI unsigned short f2bf(float f) {
  unsigned int u = __float_as_uint(f);
  u += 0x7FFFu + ((u >> 16) & 1u);
  return (unsigned short)(u >> 16);
}
DEVI float bf2f(unsigned short h) {
  return __uint_as_float(((unsigned int)h) << 16);
}

// ---------------- fp32 -> bf16 cast (float4 vectorized) ----------------
__global__ void cast_f32_bf16(const float* __restrict__ in,
                              unsigned short* __restrict__ out, int n4) {
  int i = blockIdx.x * 256 + threadIdx.x;
  if (i >= n4) return;
  float4 v = reinterpret_cast<const float4*>(in)[i];
  u16x4 o;
  o[0] = f2bf(v.x); o[1] = f2bf(v.y); o[2] = f2bf(v.z); o[3] = f2bf(v.w);
  reinterpret_cast<u16x4*>(out)[i] = o;
}

// ---------------- RoPE in place on bf16 [S][Hn*128] ----------------
__global__ void rope_kernel(unsigned short* __restrict__ X, int Hn, int total) {
  int i = blockIdx.x * 256 + threadIdx.x;
  if (i >= total) return;
  int j = i & 63;              // freq index 0..63
  int h = (i >> 6) % Hn;
  int s = i / (64 * Hn);
  float inv = powf(10000.0f, -2.0f * (float)j / 128.0f);
  float ang = (float)s * inv;
  float c = cosf(ang), sn = sinf(ang);
  unsigned short* p = X + (size_t)s * Hn * HD + h * HD;
  float x1 = bf2f(p[j]);
  float x2 = bf2f(p[j + 64]);
  p[j]      = f2bf(x1 * c - x2 * sn);
  p[j + 64] = f2bf(x2 * c + x1 * sn);
}

// ---------------- bf16 GEMM: C = A @ B^T  (A: MxK, B: NxK, row-major) ----------------
// m97 structure: 128x128 tile, BK=32, 4 waves (2x2), each wave 4x4 frags of 16x16.
template <typename OutT>
__global__ __launch_bounds__(256) void gemm_bt(
    const unsigned short* __restrict__ A,
    const unsigned short* __restrict__ B,
    OutT* __restrict__ C, int M, int N, int Kd) {
  __shared__ __align__(16) unsigned short sA[128 * 32];
  __shared__ __align__(16) unsigned short sB[128 * 32];
  const int tid = threadIdx.x;
  const int lane = tid & 63, w = tid >> 6;
  const int wr = w >> 1, wc = w & 1;
  const int lr = lane & 15, lg = lane >> 4;
  const int m0 = blockIdx.y * 128, n0 = blockIdx.x * 128;

  f32x4 acc[4][4] = {};

  for (int k0 = 0; k0 < Kd; k0 += 32) {
#pragma unroll
    for (int r = 0; r < 2; ++r) {
      int e = (tid + r * 256) * 8;   // element offset in 128x32 tile
      int row = e >> 5, col = e & 31;
      __builtin_amdgcn_global_load_lds(
          (const __attribute__((address_space(1))) void*)(A + (size_t)(m0 + row) * Kd + k0 + col),
          (__attribute__((address_space(3))) void*)(sA + e), 16, 0, 0);
      __builtin_amdgcn_global_load_lds(
          (const __attribute__((address_space(1))) void*)(B + (size_t)(n0 + row) * Kd + k0 + col),
          (__attribute__((address_space(3))) void*)(sB + e), 16, 0, 0);
    }
    __syncthreads();

    bf16x8 af[4], bfr[4];
#pragma unroll
    for (int m = 0; m < 4; ++m)
      af[m] = *reinterpret_cast<const bf16x8*>(&sA[(wr * 64 + m * 16 + lr) * 32 + lg * 8]);
#pragma unroll
    for (int n = 0; n < 4; ++n)
      bfr[n] = *reinterpret_cast<const bf16x8*>(&sB[(wc * 64 + n * 16 + lr) * 32 + lg * 8]);
#pragma unroll
    for (int m = 0; m < 4; ++m)
#pragma unroll
      for (int n = 0; n < 4; ++n)
        acc[m][n] = __builtin_amdgcn_mfma_f32_16x16x32_bf16(af[m], bfr[n], acc[m][n], 0, 0, 0);
    __syncthreads();
  }

#pragma unroll
  for (int m = 0; m < 4; ++m) {
#pragma unroll
    for (int n = 0; n < 4; ++n) {
      int gcol = n0 + wc * 64 + n * 16 + lr;
#pragma unroll
      for (int r = 0; r < 4; ++r) {
        int grow = m0 + wr * 64 + m * 16 + lg * 4 + r;
        float v = acc[m][n][r];
        if constexpr (sizeof(OutT) == 2)
          C[(size_t)grow * N + gcol] = f2bf(v);
        else
          C[(size_t)grow * N + gcol] = v;
      }
    }
  }
}

// ---------------- causal GQA flash attention ----------------
// grid: (S/64 q-tiles, 32 heads). 4 waves x 16 q-rows. KVBLK=32.
__global__ __launch_bounds__(256) void attn_kernel(
    const unsigned short* __restrict__ Q,   // [S][NH*HD]
    const unsigned short* __restrict__ Kb,  // [S][NKV*HD]
    const unsigned short* __restrict__ Vb,  // [S][NKV*HD]
    unsigned short* __restrict__ O) {       // [S][NH*HD]
  __shared__ __align__(16) unsigned short sK[32 * 128];   // XOR-swizzled
  __shared__ __align__(16) unsigned short sVT[128 * 40];  // V^T, +8 pad
  __shared__ __align__(16) unsigned short sP[4][16 * 40]; // per-wave P, +8 pad
  const int tid = threadIdx.x;
  const int lane = tid & 63, w = tid >> 6;
  const int lr = lane & 15, lg = lane >> 4;
  const int qt = blockIdx.x, h = blockIdx.y;
  const int kvh = h >> 2;
  const int qrow0 = qt * 64 + w * 16;
  const int kvstride = NKV * HD;

  // Q fragments in registers: 4 k-steps of 32 along D=128
  bf16x8 af[4];
#pragma unroll
  for (int ks = 0; ks < 4; ++ks)
    af[ks] = *reinterpret_cast<const bf16x8*>(
        &Q[(size_t)(qrow0 + lr) * HID + h * HD + ks * 32 + lg * 8]);

  f32x4 ao[8] = {};
  float mrow[4] = {-INFINITY, -INFINITY, -INFINITY, -INFINITY};
  float lrow[4] = {0.f, 0.f, 0.f, 0.f};
  const float scale = 0.08838834764831845f;  // 1/sqrt(128)

  const int nkt = 2 * qt + 2;  // causal: cover cols 0 .. qt*64+63
  for (int t = 0; t < nkt; ++t) {
    const int kv0 = t * 32;
    // stage K tile (32x128), XOR swizzle byte ^= (row&7)<<4
#pragma unroll
    for (int r = 0; r < 2; ++r) {
      int idx = tid + r * 256;            // 0..511
      int row = idx >> 4, c16 = idx & 15; // 16B chunk per thread
      bf16x8 kvv = *reinterpret_cast<const bf16x8*>(
          &Kb[(size_t)(kv0 + row) * kvstride + kvh * HD + c16 * 8]);
      int byte = (row * 256 + c16 * 16) ^ ((row & 7) << 4);
      *reinterpret_cast<bf16x8*>(reinterpret_cast<char*>(sK) + byte) = kvv;
    }
    // stage V^T (128 x 32, padded stride 40)
#pragma unroll
    for (int r = 0; r < 4; ++r) {
      int e = (tid + r * 256) * 4;
      int kvl = e >> 7, d = e & 127;
      u16x4 vv = *reinterpret_cast<const u16x4*>(
          &Vb[(size_t)(kv0 + kvl) * kvstride + kvh * HD + d]);
#pragma unroll
      for (int i2 = 0; i2 < 4; ++i2) sVT[(d + i2) * 40 + kvl] = vv[i2];
    }
    __syncthreads();

    // S = Q K^T : two 16x16 col-tiles
    f32x4 sacc[2] = {};
#pragma unroll
    for (int ks = 0; ks < 4; ++ks) {
#pragma unroll
      for (int nt = 0; nt < 2; ++nt) {
        int row = nt * 16 + lr;
        int byte = (row * 256 + ks * 64 + lg * 16) ^ ((row & 7) << 4);
        bf16x8 kf = *reinterpret_cast<const bf16x8*>(reinterpret_cast<char*>(sK) + byte);
        sacc[nt] = __builtin_amdgcn_mfma_f32_16x16x32_bf16(af[ks], kf, sacc[nt], 0, 0, 0);
      }
    }

    // online softmax (fp32)
    float p[2][4];
#pragma unroll
    for (int r = 0; r < 4; ++r) {
      int qrow = qrow0 + lg * 4 + r;
      float v0 = sacc[0][r] * scale;
      float v1 = sacc[1][r] * scale;
      if (kv0 + lr > qrow) v0 = -INFINITY;
      if (kv0 + 16 + lr > qrow) v1 = -INFINITY;
      float tmax = fmaxf(v0, v1);
#pragma unroll
      for (int off = 1; off < 16; off <<= 1)
        tmax = fmaxf(tmax, __shfl_xor(tmax, off));
      float mnew = fmaxf(mrow[r], tmax);
      float corr = __expf(mrow[r] - mnew);
      mrow[r] = mnew;
      float p0 = __expf(v0 - mnew);
      float p1 = __expf(v1 - mnew);
      float rs = p0 + p1;
#pragma unroll
      for (int off = 1; off < 16; off <<= 1) rs += __shfl_xor(rs, off);
      lrow[r] = lrow[r] * corr + rs;
#pragma unroll
      for (int dt = 0; dt < 8; ++dt) ao[dt][r] *= corr;
      p[0][r] = p0; p[1][r] = p1;
    }

    // P -> LDS (bf16), then PV
    unsigned short* pbuf = sP[w];
#pragma unroll
    for (int nt = 0; nt < 2; ++nt)
#pragma unroll
      for (int r = 0; r < 4; ++r)
        pbuf[(lg * 4 + r) * 40 + nt * 16 + lr] = f2bf(p[nt][r]);
    asm volatile("s_waitcnt lgkmcnt(0)" ::: "memory");
    bf16x8 pf = *reinterpret_cast<const bf16x8*>(&pbuf[lr * 40 + lg * 8]);
#pragma unroll
    for (int dt = 0; dt < 8; ++dt) {
      bf16x8 vf = *reinterpret_cast<const bf16x8*>(&sVT[(dt * 16 + lr) * 40 + lg * 8]);
      ao[dt] = __builtin_amdgcn_mfma_f32_16x16x32_bf16(pf, vf, ao[dt], 0, 0, 0);
    }
    __syncthreads();
  }

  // epilogue: divide by l, store bf16
#pragma unroll
  for (int dt = 0; dt < 8; ++dt) {
#pragma unroll
    for (int r = 0; r < 4; ++r) {
      float outv = ao[dt][r] / lrow[r];
      int row = qrow0 + lg * 4 + r;
      int col = h * HD + dt * 16 + lr;
      O[(size_t)row * HID + col] = f2bf(outv);
    }
  }
}

// ---------------- launch ----------------
extern "C" void kernel_launch(void* const* d_in, const int* in_sizes, int n_in,
                              void* d_out, int out_size, void* d_ws, size_t ws_size,
                              hipStream_t stream) {
  const float* hs = (const float*)d_in[0];
  // d_in[1] = position_ids (arange, unused: positions derived from row index)
  const float* Wq = (const float*)d_in[2];
  const float* Wk = (const float*)d_in[3];
  const float* Wv = (const float*)d_in[4];
  const float* Wo = (const float*)d_in[5];

  unsigned short* ws = (unsigned short*)d_ws;
  size_t off = 0;
  unsigned short* H16   = ws + off; off += (size_t)S_LEN * HID;        // also reused as attn-out
  unsigned short* Wqo16 = ws + off; off += (size_t)HID * HID;          // Wq, later Wo
  unsigned short* Wk16  = ws + off; off += (size_t)NKV * HD * HID;
  unsigned short* Wv16  = ws + off; off += (size_t)NKV * HD * HID;
  unsigned short* Qb    = ws + off; off += (size_t)S_LEN * NH * HD;
  unsigned short* Kb    = ws + off; off += (size_t)S_LEN * NKV * HD;
  unsigned short* Vb    = ws + off; off += (size_t)S_LEN * NKV * HD;

  auto cast = [&](const float* src, unsigned short* dst, size_t n) {
    int n4 = (int)(n / 4);
    cast_f32_bf16<<<(n4 + 255) / 256, 256, 0, stream>>>(src, dst, n4);
  };

  cast(hs, H16, (size_t)S_LEN * HID);
  cast(Wq, Wqo16, (size_t)HID * HID);
  cast(Wk, Wk16, (size_t)NKV * HD * HID);
  cast(Wv, Wv16, (size_t)NKV * HD * HID);

  // QKV projections
  gemm_bt<unsigned short><<<dim3(HID / 128, S_LEN / 128), 256, 0, stream>>>(
      H16, Wqo16, Qb, S_LEN, HID, HID);
  gemm_bt<unsigned short><<<dim3(NKV * HD / 128, S_LEN / 128), 256, 0, stream>>>(
      H16, Wk16, Kb, S_LEN, NKV * HD, HID);
  gemm_bt<unsigned short><<<dim3(NKV * HD / 128, S_LEN / 128), 256, 0, stream>>>(
      H16, Wv16, Vb, S_LEN, NKV * HD, HID);

  // Wo cast (reuses Wq buffer; stream-ordered after Q GEMM)
  cast(Wo, Wqo16, (size_t)HID * HID);

  // RoPE
  {
    int totq = S_LEN * NH * 64;
    rope_kernel<<<(totq + 255) / 256, 256, 0, stream>>>(Qb, NH, totq);
    int totk = S_LEN * NKV * 64;
    rope_kernel<<<(totk + 255) / 256, 256, 0, stream>>>(Kb, NKV, totk);
  }

  // attention -> H16 (reused as [S][HID] bf16)
  attn_kernel<<<dim3(S_LEN / 64, NH), 256, 0, stream>>>(Qb, Kb, Vb, H16);

  // output projection -> fp32 d_out
  gemm_bt<float><<<dim3(HID / 128, S_LEN / 128), 256, 0, stream>>>(
      H16, Wqo16, (float*)d_out, S_LEN, HID, HID);
}

// Round 2
// 676.782 us; speedup vs baseline: 1.3369x; 1.3369x over previous
//
#include <hip/hip_runtime.h>

typedef __attribute__((ext_vector_type(4))) float f32x4;
typedef __attribute__((ext_vector_type(8))) __bf16 bf16x8;
typedef __attribute__((ext_vector_type(4))) unsigned short u16x4;

#define DEVI static __device__ __forceinline__

static constexpr int S_LEN = 2048;
static constexpr int HID   = 4096;
static constexpr int NH    = 32;
static constexpr int NKV   = 8;
static constexpr int HD    = 128;

DEVI unsigned short f2bf(float f) {
  unsigned int u = __float_as_uint(f);
  u += 0x7FFFu + ((u >> 16) & 1u);
  return (unsigned short)(u >> 16);
}
DEVI float bf2f(unsigned short h) {
  return __uint_as_float(((unsigned int)h) << 16);
}

// ---------------- fp32 -> bf16 cast (float4 vectorized) ----------------
__global__ void cast_f32_bf16(const float* __restrict__ in,
                              unsigned short* __restrict__ out, int n4) {
  int i = blockIdx.x * 256 + threadIdx.x;
  if (i >= n4) return;
  float4 v = reinterpret_cast<const float4*>(in)[i];
  u16x4 o;
  o[0] = f2bf(v.x); o[1] = f2bf(v.y); o[2] = f2bf(v.z); o[3] = f2bf(v.w);
  reinterpret_cast<u16x4*>(out)[i] = o;
}

// ---------------- RoPE in place on bf16 [S][Hn*128] ----------------
__global__ void rope_kernel(unsigned short* __restrict__ X, int Hn, int total) {
  int i = blockIdx.x * 256 + threadIdx.x;
  if (i >= total) return;
  int j = i & 63;              // freq index 0..63
  int h = (i >> 6) % Hn;
  int s = i / (64 * Hn);
  float inv = powf(10000.0f, -2.0f * (float)j / 128.0f);
  float ang = (float)s * inv;
  float c = cosf(ang), sn = sinf(ang);
  unsigned short* p = X + (size_t)s * Hn * HD + h * HD;
  float x1 = bf2f(p[j]);
  float x2 = bf2f(p[j + 64]);
  p[j]      = f2bf(x1 * c - x2 * sn);
  p[j + 64] = f2bf(x2 * c + x1 * sn);
}

// ---------------- bf16 GEMM: C = A @ B^T  (A: MxK, B: NxK, row-major) ----------------
// m97 structure: 128x128 tile, BK=32, 4 waves (2x2), each wave 4x4 frags of 16x16.
// TR=true writes C^T (N x M) instead — used to produce V^T for attention.
template <typename OutT, bool TR = false>
__global__ __launch_bounds__(256) void gemm_bt(
    const unsigned short* __restrict__ A,
    const unsigned short* __restrict__ B,
    OutT* __restrict__ C, int M, int N, int Kd) {
  __shared__ __align__(16) unsigned short sA[128 * 32];
  __shared__ __align__(16) unsigned short sB[128 * 32];
  const int tid = threadIdx.x;
  const int lane = tid & 63, w = tid >> 6;
  const int wr = w >> 1, wc = w & 1;
  const int lr = lane & 15, lg = lane >> 4;
  const int m0 = blockIdx.y * 128, n0 = blockIdx.x * 128;

  f32x4 acc[4][4] = {};

  for (int k0 = 0; k0 < Kd; k0 += 32) {
#pragma unroll
    for (int r = 0; r < 2; ++r) {
      int e = (tid + r * 256) * 8;   // element offset in 128x32 tile
      int row = e >> 5, col = e & 31;
      __builtin_amdgcn_global_load_lds(
          (const __attribute__((address_space(1))) void*)(A + (size_t)(m0 + row) * Kd + k0 + col),
          (__attribute__((address_space(3))) void*)(sA + e), 16, 0, 0);
      __builtin_amdgcn_global_load_lds(
          (const __attribute__((address_space(1))) void*)(B + (size_t)(n0 + row) * Kd + k0 + col),
          (__attribute__((address_space(3))) void*)(sB + e), 16, 0, 0);
    }
    __syncthreads();

    bf16x8 af[4], bfr[4];
#pragma unroll
    for (int m = 0; m < 4; ++m)
      af[m] = *reinterpret_cast<const bf16x8*>(&sA[(wr * 64 + m * 16 + lr) * 32 + lg * 8]);
#pragma unroll
    for (int n = 0; n < 4; ++n)
      bfr[n] = *reinterpret_cast<const bf16x8*>(&sB[(wc * 64 + n * 16 + lr) * 32 + lg * 8]);
#pragma unroll
    for (int m = 0; m < 4; ++m)
#pragma unroll
      for (int n = 0; n < 4; ++n)
        acc[m][n] = __builtin_amdgcn_mfma_f32_16x16x32_bf16(af[m], bfr[n], acc[m][n], 0, 0, 0);
    __syncthreads();
  }

#pragma unroll
  for (int m = 0; m < 4; ++m) {
#pragma unroll
    for (int n = 0; n < 4; ++n) {
      int gcol = n0 + wc * 64 + n * 16 + lr;
      if constexpr (TR) {
        int growb = m0 + wr * 64 + m * 16 + lg * 4;
        u16x4 o4;
#pragma unroll
        for (int r = 0; r < 4; ++r) o4[r] = f2bf(acc[m][n][r]);
        *reinterpret_cast<u16x4*>(&C[(size_t)gcol * M + growb]) = o4;
      } else {
#pragma unroll
        for (int r = 0; r < 4; ++r) {
          int grow = m0 + wr * 64 + m * 16 + lg * 4 + r;
          float v = acc[m][n][r];
          if constexpr (sizeof(OutT) == 2)
            C[(size_t)grow * N + gcol] = f2bf(v);
          else
            C[(size_t)grow * N + gcol] = v;
        }
      }
    }
  }
}

// ---------------- causal GQA flash attention, swapped-QK^T ----------------
// grid: (16 q-blocks of 128 rows, 32 heads). 4 waves x 32 q-rows (2 q-tiles of 16).
// KVBLK=64, double-buffered LDS, XOR-swizzled K and V^T tiles.
// Swapped: S^T = mfma(K, Q) -> lane owns q-col (lane&15); softmax = 2 shfl_xor.
// PV: O^T = mfma(V^T, P^T); P redistributed in-register via 8 shfl per 32-k group.
__global__ __launch_bounds__(256) void attn_kernel(
    const unsigned short* __restrict__ Q,   // [S][NH*HD]
    const unsigned short* __restrict__ Kb,  // [S][NKV*HD]
    const unsigned short* __restrict__ Vt,  // [NKV*HD][S]  (V transposed)
    unsigned short* __restrict__ O) {       // [S][NH*HD]
  __shared__ __align__(16) unsigned short sK[2][64 * 128];
  __shared__ __align__(16) unsigned short sV[2][128 * 64];
  const int tid = threadIdx.x;
  const int lane = tid & 63, w = tid >> 6;
  const int lr = lane & 15, lg = lane >> 4;
  const int qt = (int)gridDim.x - 1 - (int)blockIdx.x;  // descending work order
  const int h = blockIdx.y, kvh = h >> 2;
  const int q0 = qt * 128, qw = q0 + w * 32;
  const int KVS = NKV * HD;

  // Q fragments (B-operand of swapped QK^T): lane holds Q[qw+q2*16+lr][ks*32+lg*8+i]
  bf16x8 qf[2][4];
#pragma unroll
  for (int q2 = 0; q2 < 2; ++q2)
#pragma unroll
    for (int ks = 0; ks < 4; ++ks)
      qf[q2][ks] = *reinterpret_cast<const bf16x8*>(
          &Q[(size_t)(qw + q2 * 16 + lr) * HID + h * HD + ks * 32 + lg * 8]);

  f32x4 ao[2][8] = {};                 // O^T accum: lane owns q=lr, d = dt*16+lg*4+r
  float mrun[2] = {-INFINITY, -INFINITY};
  float lrun[2] = {0.f, 0.f};
  const float scale = 0.08838834764831845f;  // 1/sqrt(128)
  const int ntiles = 2 * qt + 2;

  // Stage K tile [64][128] and V^T tile [128][64], XOR-swizzle via pre-swizzled
  // global source (rule 21): LDS stays linear for global_load_lds.
  auto stage = [&](int b, int kv0) {
#pragma unroll
    for (int i = 0; i < 4; ++i) {
      int off = (tid + i * 256) * 8;
      int r = off >> 7, c = (off >> 3) & 15;   // K row, 8-elem chunk
      __builtin_amdgcn_global_load_lds(
          (const __attribute__((address_space(1))) void*)(
              Kb + (size_t)(kv0 + r) * KVS + kvh * HD + ((c ^ (r & 7)) * 8)),
          (__attribute__((address_space(3))) void*)(&sK[b][off]), 16, 0, 0);
    }
#pragma unroll
    for (int i = 0; i < 4; ++i) {
      int off = (tid + i * 256) * 8;
      int r = off >> 6, c = (off >> 3) & 7;    // V^T row (=d), 8-elem chunk
      __builtin_amdgcn_global_load_lds(
          (const __attribute__((address_space(1))) void*)(
              Vt + (size_t)(kvh * HD + r) * S_LEN + kv0 + ((c ^ (r & 7)) * 8)),
          (__attribute__((address_space(3))) void*)(&sV[b][off]), 16, 0, 0);
    }
  };

  stage(0, 0);
  __syncthreads();
  int cur = 0;

  for (int t = 0; t < ntiles; ++t) {
    const int kv0 = t * 64;
    if (t + 1 < ntiles) stage(cur ^ 1, kv0 + 64);

    // ---- S^T = K · Q^T : sacc[q2][ktile], lane holds S^T[kt*16+lg*4+r][q=lr]
    f32x4 sacc[2][4] = {};
#pragma unroll
    for (int kt = 0; kt < 4; ++kt) {
#pragma unroll
      for (int ks = 0; ks < 4; ++ks) {
        int elem = (kt * 16 + lr) * 128 + (((4 * ks + lg) ^ (lr & 7)) * 8);
        bf16x8 kf = *reinterpret_cast<const bf16x8*>(&sK[cur][elem]);
        sacc[0][kt] = __builtin_amdgcn_mfma_f32_16x16x32_bf16(kf, qf[0][ks], sacc[0][kt], 0, 0, 0);
        sacc[1][kt] = __builtin_amdgcn_mfma_f32_16x16x32_bf16(kf, qf[1][ks], sacc[1][kt], 0, 0, 0);
      }
    }

    const bool maskT = (t >= ntiles - 2);  // only last two tiles touch the diagonal
    unsigned int bfrag[2][2][4];           // PV B-operand [q2][k-group][4 regs]
#pragma unroll
    for (int q2 = 0; q2 < 2; ++q2) {
      const int qg = qw + q2 * 16 + lr;
      float p[16];
      float tmax = -INFINITY;
#pragma unroll
      for (int kt = 0; kt < 4; ++kt)
#pragma unroll
        for (int r = 0; r < 4; ++r) {
          float v = sacc[q2][kt][r] * scale;
          if (maskT && (kv0 + kt * 16 + lg * 4 + r > qg)) v = -INFINITY;
          p[kt * 4 + r] = v;
          tmax = fmaxf(tmax, v);
        }
      // cross-lg reduce (lanes sharing q differ only in bits 4,5)
      tmax = fmaxf(tmax, __shfl_xor(tmax, 16));
      tmax = fmaxf(tmax, __shfl_xor(tmax, 32));
      float mnew = fmaxf(mrun[q2], tmax);
      float corr = __expf(mrun[q2] - mnew);
      mrun[q2] = mnew;
      float rs = 0.f;
#pragma unroll
      for (int i = 0; i < 16; ++i) { p[i] = __expf(p[i] - mnew); rs += p[i]; }
      rs += __shfl_xor(rs, 16);
      rs += __shfl_xor(rs, 32);
      lrun[q2] = lrun[q2] * corr + rs;
#pragma unroll
      for (int dt = 0; dt < 8; ++dt) ao[q2][dt] *= corr;

      // pack p -> bf16 pairs, redistribute into PV B-operand layout:
      // dest lane (q,lg) reg j needs k-in-group = 8*lg + 2j(,+1)
#pragma unroll
      for (int g = 0; g < 2; ++g) {
        unsigned int Au = (unsigned)f2bf(p[8 * g + 0]) | ((unsigned)f2bf(p[8 * g + 1]) << 16);
        unsigned int Bu = (unsigned)f2bf(p[8 * g + 2]) | ((unsigned)f2bf(p[8 * g + 3]) << 16);
        unsigned int Cu = (unsigned)f2bf(p[8 * g + 4]) | ((unsigned)f2bf(p[8 * g + 5]) << 16);
        unsigned int Du = (unsigned)f2bf(p[8 * g + 6]) | ((unsigned)f2bf(p[8 * g + 7]) << 16);
        int s0 = (lg & 1) * 2;
        int src0 = lr + 16 * s0, src1 = src0 + 16;
        bool hi = lg >= 2;
        int a0 = __shfl((int)Au, src0), c0 = __shfl((int)Cu, src0);
        int b0 = __shfl((int)Bu, src0), d0 = __shfl((int)Du, src0);
        int a1 = __shfl((int)Au, src1), c1 = __shfl((int)Cu, src1);
        int b1 = __shfl((int)Bu, src1), d1 = __shfl((int)Du, src1);
        bfrag[q2][g][0] = hi ? (unsigned)c0 : (unsigned)a0;
        bfrag[q2][g][1] = hi ? (unsigned)d0 : (unsigned)b0;
        bfrag[q2][g][2] = hi ? (unsigned)c1 : (unsigned)a1;
        bfrag[q2][g][3] = hi ? (unsigned)d1 : (unsigned)b1;
      }
    }

    // ---- O^T += V^T · P^T
#pragma unroll
    for (int g = 0; g < 2; ++g) {
#pragma unroll
      for (int dt = 0; dt < 8; ++dt) {
        int d = dt * 16 + lr;
        int elem = d * 64 + (((4 * g + lg) ^ (d & 7)) * 8);
        bf16x8 vf = *reinterpret_cast<const bf16x8*>(&sV[cur][elem]);
        ao[0][dt] = __builtin_amdgcn_mfma_f32_16x16x32_bf16(
            vf, *reinterpret_cast<const bf16x8*>(&bfrag[0][g]), ao[0][dt], 0, 0, 0);
        ao[1][dt] = __builtin_amdgcn_mfma_f32_16x16x32_bf16(
            vf, *reinterpret_cast<const bf16x8*>(&bfrag[1][g]), ao[1][dt], 0, 0, 0);
      }
    }
    __syncthreads();
    cur ^= 1;
  }

  // epilogue: divide by l, store bf16 (lane q=lr, d = dt*16+lg*4+r -> 8B stores)
#pragma unroll
  for (int q2 = 0; q2 < 2; ++q2) {
    float inv = 1.0f / lrun[q2];
    int qrow = qw + q2 * 16 + lr;
#pragma unroll
    for (int dt = 0; dt < 8; ++dt) {
      u16x4 o4;
#pragma unroll
      for (int r = 0; r < 4; ++r) o4[r] = f2bf(ao[q2][dt][r] * inv);
      *reinterpret_cast<u16x4*>(&O[(size_t)qrow * HID + h * HD + dt * 16 + lg * 4]) = o4;
    }
  }
}

// ---------------- launch ----------------
extern "C" void kernel_launch(void* const* d_in, const int* in_sizes, int n_in,
                              void* d_out, int out_size, void* d_ws, size_t ws_size,
                              hipStream_t stream) {
  const float* hs = (const float*)d_in[0];
  // d_in[1] = position_ids (arange, unused: positions derived from row index)
  const float* Wq = (const float*)d_in[2];
  const float* Wk = (const float*)d_in[3];
  const float* Wv = (const float*)d_in[4];
  const float* Wo = (const float*)d_in[5];

  unsigned short* ws = (unsigned short*)d_ws;
  size_t off = 0;
  unsigned short* H16   = ws + off; off += (size_t)S_LEN * HID;        // also reused as attn-out
  unsigned short* Wqo16 = ws + off; off += (size_t)HID * HID;          // Wq, later Wo
  unsigned short* Wk16  = ws + off; off += (size_t)NKV * HD * HID;
  unsigned short* Wv16  = ws + off; off += (size_t)NKV * HD * HID;
  unsigned short* Qb    = ws + off; off += (size_t)S_LEN * NH * HD;
  unsigned short* Kb    = ws + off; off += (size_t)S_LEN * NKV * HD;
  unsigned short* Vt    = ws + off; off += (size_t)S_LEN * NKV * HD;   // V^T [NKV*HD][S]

  auto cast = [&](const float* src, unsigned short* dst, size_t n) {
    int n4 = (int)(n / 4);
    cast_f32_bf16<<<(n4 + 255) / 256, 256, 0, stream>>>(src, dst, n4);
  };

  cast(hs, H16, (size_t)S_LEN * HID);
  cast(Wq, Wqo16, (size_t)HID * HID);
  cast(Wk, Wk16, (size_t)NKV * HD * HID);
  cast(Wv, Wv16, (size_t)NKV * HD * HID);

  // QKV projections (V written transposed for attention's PV operand)
  gemm_bt<unsigned short><<<dim3(HID / 128, S_LEN / 128), 256, 0, stream>>>(
      H16, Wqo16, Qb, S_LEN, HID, HID);
  gemm_bt<unsigned short><<<dim3(NKV * HD / 128, S_LEN / 128), 256, 0, stream>>>(
      H16, Wk16, Kb, S_LEN, NKV * HD, HID);
  gemm_bt<unsigned short, true><<<dim3(NKV * HD / 128, S_LEN / 128), 256, 0, stream>>>(
      H16, Wv16, Vt, S_LEN, NKV * HD, HID);

  // Wo cast (reuses Wq buffer; stream-ordered after Q GEMM)
  cast(Wo, Wqo16, (size_t)HID * HID);

  // RoPE on Q and K only
  {
    int totq = S_LEN * NH * 64;
    rope_kernel<<<(totq + 255) / 256, 256, 0, stream>>>(Qb, NH, totq);
    int totk = S_LEN * NKV * 64;
    rope_kernel<<<(totk + 255) / 256, 256, 0, stream>>>(Kb, NKV, totk);
  }

  // attention -> H16 (reused as [S][HID] bf16)
  attn_kernel<<<dim3(S_LEN / 128, NH), 256, 0, stream>>>(Qb, Kb, Vt, H16);

  // output projection -> fp32 d_out
  gemm_bt<float><<<dim3(HID / 128, S_LEN / 128), 256, 0, stream>>>(
      H16, Wqo16, (float*)d_out, S_LEN, HID, HID);
}

// Round 3
// 407.066 us; speedup vs baseline: 2.2227x; 1.6626x over previous
//
#include <hip/hip_runtime.h>

typedef __attribute__((ext_vector_type(4))) float f32x4;
typedef __attribute__((ext_vector_type(8))) __bf16 bf16x8;
typedef __attribute__((ext_vector_type(4))) unsigned short u16x4;

#define DEVI static __device__ __forceinline__

static constexpr int S_LEN = 2048;
static constexpr int HID   = 4096;
static constexpr int NH    = 32;
static constexpr int NKV   = 8;
static constexpr int HD    = 128;
static constexpr int NQKV  = HID + 2 * NKV * HD;   // 6144

DEVI unsigned short f2bf(float f) {
  unsigned int u = __float_as_uint(f);
  u += 0x7FFFu + ((u >> 16) & 1u);
  return (unsigned short)(u >> 16);
}
DEVI float bf2f(unsigned short h) {
  return __uint_as_float(((unsigned int)h) << 16);
}

// ---------------- fp32 -> bf16 cast (float4 vectorized) ----------------
__global__ void cast_f32_bf16(const float* __restrict__ in,
                              unsigned short* __restrict__ out, int n4) {
  int i = blockIdx.x * 256 + threadIdx.x;
  if (i >= n4) return;
  float4 v = reinterpret_cast<const float4*>(in)[i];
  u16x4 o;
  o[0] = f2bf(v.x); o[1] = f2bf(v.y); o[2] = f2bf(v.z); o[3] = f2bf(v.w);
  reinterpret_cast<u16x4*>(out)[i] = o;
}

// ---------------- RoPE cos/sin table [S][64] float2 ----------------
__global__ void rope_table(float2* __restrict__ tab) {
  int i = blockIdx.x * 256 + threadIdx.x;
  if (i >= S_LEN * 64) return;
  int j = i & 63, s = i >> 6;
  float inv = powf(10000.0f, -(float)j / 64.0f);
  float ang = (float)s * inv;
  tab[i] = make_float2(cosf(ang), sinf(ang));
}

// ---------------- RoPE in place on bf16 [S][Hn*128] ----------------
__global__ void rope_kernel(unsigned short* __restrict__ X,
                            const float2* __restrict__ tab, int Hn, int total) {
  int i = blockIdx.x * 256 + threadIdx.x;
  if (i >= total) return;
  int j = i & 63;              // freq index 0..63
  int h = (i >> 6) % Hn;
  int s = i / (64 * Hn);
  float2 cs = tab[s * 64 + j];
  unsigned short* p = X + (size_t)s * Hn * HD + h * HD;
  float x1 = bf2f(p[j]);
  float x2 = bf2f(p[j + 64]);
  p[j]      = f2bf(x1 * cs.x - x2 * cs.y);
  p[j + 64] = f2bf(x2 * cs.x + x1 * cs.y);
}

// ---------------- fused QKV GEMM: [2048 x 6144] = H @ Wcat^T ----------------
// m97 structure: 128x128 tile, BK=32, 4 waves (2x2), each wave 4x4 frags of 16x16.
// Epilogue routes per-block: cols <4096 -> Qb; <5120 -> Kb; else V^T -> Vt.
__global__ __launch_bounds__(256) void gemm_qkv(
    const unsigned short* __restrict__ A,
    const unsigned short* __restrict__ B,
    unsigned short* __restrict__ Qb,
    unsigned short* __restrict__ Kb,
    unsigned short* __restrict__ Vt) {
  __shared__ __align__(16) unsigned short sA[128 * 32];
  __shared__ __align__(16) unsigned short sB[128 * 32];
  const int tid = threadIdx.x;
  const int lane = tid & 63, w = tid >> 6;
  const int wr = w >> 1, wc = w & 1;
  const int lr = lane & 15, lg = lane >> 4;
  const int m0 = blockIdx.y * 128, n0 = blockIdx.x * 128;
  const int Kd = HID;

  f32x4 acc[4][4] = {};

  for (int k0 = 0; k0 < Kd; k0 += 32) {
#pragma unroll
    for (int r = 0; r < 2; ++r) {
      int e = (tid + r * 256) * 8;
      int row = e >> 5, col = e & 31;
      __builtin_amdgcn_global_load_lds(
          (const __attribute__((address_space(1))) void*)(A + (size_t)(m0 + row) * Kd + k0 + col),
          (__attribute__((address_space(3))) void*)(sA + e), 16, 0, 0);
      __builtin_amdgcn_global_load_lds(
          (const __attribute__((address_space(1))) void*)(B + (size_t)(n0 + row) * Kd + k0 + col),
          (__attribute__((address_space(3))) void*)(sB + e), 16, 0, 0);
    }
    __syncthreads();

    bf16x8 af[4], bfr[4];
#pragma unroll
    for (int m = 0; m < 4; ++m)
      af[m] = *reinterpret_cast<const bf16x8*>(&sA[(wr * 64 + m * 16 + lr) * 32 + lg * 8]);
#pragma unroll
    for (int n = 0; n < 4; ++n)
      bfr[n] = *reinterpret_cast<const bf16x8*>(&sB[(wc * 64 + n * 16 + lr) * 32 + lg * 8]);
#pragma unroll
    for (int m = 0; m < 4; ++m)
#pragma unroll
      for (int n = 0; n < 4; ++n)
        acc[m][n] = __builtin_amdgcn_mfma_f32_16x16x32_bf16(af[m], bfr[n], acc[m][n], 0, 0, 0);
    __syncthreads();
  }

#pragma unroll
  for (int m = 0; m < 4; ++m) {
#pragma unroll
    for (int n = 0; n < 4; ++n) {
      int gcol = n0 + wc * 64 + n * 16 + lr;
      int growb = m0 + wr * 64 + m * 16 + lg * 4;
      if (n0 < HID) {                         // Q region
#pragma unroll
        for (int r = 0; r < 4; ++r)
          Qb[(size_t)(growb + r) * HID + gcol] = f2bf(acc[m][n][r]);
      } else if (n0 < HID + NKV * HD) {       // K region
#pragma unroll
        for (int r = 0; r < 4; ++r)
          Kb[(size_t)(growb + r) * (NKV * HD) + (gcol - HID)] = f2bf(acc[m][n][r]);
      } else {                                // V region, transposed
        u16x4 o4;
#pragma unroll
        for (int r = 0; r < 4; ++r) o4[r] = f2bf(acc[m][n][r]);
        *reinterpret_cast<u16x4*>(
            &Vt[(size_t)(gcol - HID - NKV * HD) * S_LEN + growb]) = o4;
      }
    }
  }
}

// ---------------- bf16 GEMM: C = A @ B^T (O-projection, fp32 out) ----------------
__global__ __launch_bounds__(256) void gemm_bt(
    const unsigned short* __restrict__ A,
    const unsigned short* __restrict__ B,
    float* __restrict__ C, int M, int N, int Kd) {
  __shared__ __align__(16) unsigned short sA[128 * 32];
  __shared__ __align__(16) unsigned short sB[128 * 32];
  const int tid = threadIdx.x;
  const int lane = tid & 63, w = tid >> 6;
  const int wr = w >> 1, wc = w & 1;
  const int lr = lane & 15, lg = lane >> 4;
  const int m0 = blockIdx.y * 128, n0 = blockIdx.x * 128;

  f32x4 acc[4][4] = {};

  for (int k0 = 0; k0 < Kd; k0 += 32) {
#pragma unroll
    for (int r = 0; r < 2; ++r) {
      int e = (tid + r * 256) * 8;
      int row = e >> 5, col = e & 31;
      __builtin_amdgcn_global_load_lds(
          (const __attribute__((address_space(1))) void*)(A + (size_t)(m0 + row) * Kd + k0 + col),
          (__attribute__((address_space(3))) void*)(sA + e), 16, 0, 0);
      __builtin_amdgcn_global_load_lds(
          (const __attribute__((address_space(1))) void*)(B + (size_t)(n0 + row) * Kd + k0 + col),
          (__attribute__((address_space(3))) void*)(sB + e), 16, 0, 0);
    }
    __syncthreads();

    bf16x8 af[4], bfr[4];
#pragma unroll
    for (int m = 0; m < 4; ++m)
      af[m] = *reinterpret_cast<const bf16x8*>(&sA[(wr * 64 + m * 16 + lr) * 32 + lg * 8]);
#pragma unroll
    for (int n = 0; n < 4; ++n)
      bfr[n] = *reinterpret_cast<const bf16x8*>(&sB[(wc * 64 + n * 16 + lr) * 32 + lg * 8]);
#pragma unroll
    for (int m = 0; m < 4; ++m)
#pragma unroll
      for (int n = 0; n < 4; ++n)
        acc[m][n] = __builtin_amdgcn_mfma_f32_16x16x32_bf16(af[m], bfr[n], acc[m][n], 0, 0, 0);
    __syncthreads();
  }

#pragma unroll
  for (int m = 0; m < 4; ++m)
#pragma unroll
    for (int n = 0; n < 4; ++n) {
      int gcol = n0 + wc * 64 + n * 16 + lr;
#pragma unroll
      for (int r = 0; r < 4; ++r) {
        int grow = m0 + wr * 64 + m * 16 + lg * 4 + r;
        C[(size_t)grow * N + gcol] = acc[m][n][r];
      }
    }
}

// ---------------- causal GQA flash attention, swapped-QK^T, 8-wave ----------------
// grid: (16 q-blocks of 128 rows, 32 heads). 8 waves x 16 q-rows (1 q-tile each).
// KVBLK=64, double-buffered LDS, XOR-swizzled K and V^T tiles (pre-swizzled source).
__global__ __launch_bounds__(512, 4) void attn_kernel(
    const unsigned short* __restrict__ Q,   // [S][NH*HD]
    const unsigned short* __restrict__ Kb,  // [S][NKV*HD]
    const unsigned short* __restrict__ Vt,  // [NKV*HD][S]
    unsigned short* __restrict__ O) {       // [S][NH*HD]
  __shared__ __align__(16) unsigned short sK[2][64 * 128];
  __shared__ __align__(16) unsigned short sV[2][128 * 64];
  const int tid = threadIdx.x;
  const int lane = tid & 63, w = tid >> 6;
  const int lr = lane & 15, lg = lane >> 4;
  const int qt = (int)gridDim.x - 1 - (int)blockIdx.x;  // descending work order
  const int h = blockIdx.y, kvh = h >> 2;
  const int q0 = qt * 128, qw = q0 + w * 16;
  const int KVS = NKV * HD;

  // Q fragments (B-operand of swapped QK^T): lane holds Q[qw+lr][ks*32+lg*8+i]
  bf16x8 qf[4];
#pragma unroll
  for (int ks = 0; ks < 4; ++ks)
    qf[ks] = *reinterpret_cast<const bf16x8*>(
        &Q[(size_t)(qw + lr) * HID + h * HD + ks * 32 + lg * 8]);

  f32x4 ao[8] = {};                    // O^T accum: lane owns q=lr, d = dt*16+lg*4+r
  float mrun = -INFINITY, lrun = 0.f;
  const float scale = 0.08838834764831845f;  // 1/sqrt(128)
  const int ntiles = 2 * qt + 2;

  auto stage = [&](int b, int kv0) {
#pragma unroll
    for (int i = 0; i < 2; ++i) {
      int off = (tid + i * 512) * 8;
      int r = off >> 7, c = (off >> 3) & 15;   // K row, 8-elem chunk
      __builtin_amdgcn_global_load_lds(
          (const __attribute__((address_space(1))) void*)(
              Kb + (size_t)(kv0 + r) * KVS + kvh * HD + ((c ^ (r & 7)) * 8)),
          (__attribute__((address_space(3))) void*)(&sK[b][off]), 16, 0, 0);
    }
#pragma unroll
    for (int i = 0; i < 2; ++i) {
      int off = (tid + i * 512) * 8;
      int r = off >> 6, c = (off >> 3) & 7;    // V^T row (=d), 8-elem chunk
      __builtin_amdgcn_global_load_lds(
          (const __attribute__((address_space(1))) void*)(
              Vt + (size_t)(kvh * HD + r) * S_LEN + kv0 + ((c ^ (r & 7)) * 8)),
          (__attribute__((address_space(3))) void*)(&sV[b][off]), 16, 0, 0);
    }
  };

  stage(0, 0);
  __syncthreads();
  int cur = 0;

  for (int t = 0; t < ntiles; ++t) {
    const int kv0 = t * 64;
    if (t + 1 < ntiles) stage(cur ^ 1, kv0 + 64);

    if (kv0 <= qw + 15) {  // tile not fully masked for this wave
      // ---- S^T = K · Q^T : lane holds S^T[kt*16+lg*4+r][q=lr]
      f32x4 sacc[4] = {};
      __builtin_amdgcn_s_setprio(1);
#pragma unroll
      for (int kt = 0; kt < 4; ++kt)
#pragma unroll
        for (int ks = 0; ks < 4; ++ks) {
          int elem = (kt * 16 + lr) * 128 + (((4 * ks + lg) ^ (lr & 7)) * 8);
          bf16x8 kf = *reinterpret_cast<const bf16x8*>(&sK[cur][elem]);
          sacc[kt] = __builtin_amdgcn_mfma_f32_16x16x32_bf16(kf, qf[ks], sacc[kt], 0, 0, 0);
        }
      __builtin_amdgcn_s_setprio(0);

      // ---- online softmax (fp32)
      const bool needMask = (kv0 + 63 > qw);
      const int qg = qw + lr;
      float p[16];
      float tmax = -INFINITY;
#pragma unroll
      for (int kt = 0; kt < 4; ++kt)
#pragma unroll
        for (int r = 0; r < 4; ++r) {
          float v = sacc[kt][r] * scale;
          if (needMask && (kv0 + kt * 16 + lg * 4 + r > qg)) v = -INFINITY;
          p[kt * 4 + r] = v;
          tmax = fmaxf(tmax, v);
        }
      tmax = fmaxf(tmax, __shfl_xor(tmax, 16));
      tmax = fmaxf(tmax, __shfl_xor(tmax, 32));
      float mnew = fmaxf(mrun, tmax);
      float corr = __expf(mrun - mnew);
      mrun = mnew;
      float rs = 0.f;
#pragma unroll
      for (int i = 0; i < 16; ++i) { p[i] = __expf(p[i] - mnew); rs += p[i]; }
      rs += __shfl_xor(rs, 16);
      rs += __shfl_xor(rs, 32);
      lrun = lrun * corr + rs;
#pragma unroll
      for (int dt = 0; dt < 8; ++dt) ao[dt] *= corr;

      // ---- pack p -> bf16, redistribute into PV B-operand layout
      unsigned int bfrag[2][4];
#pragma unroll
      for (int g = 0; g < 2; ++g) {
        unsigned int Au = (unsigned)f2bf(p[8 * g + 0]) | ((unsigned)f2bf(p[8 * g + 1]) << 16);
        unsigned int Bu = (unsigned)f2bf(p[8 * g + 2]) | ((unsigned)f2bf(p[8 * g + 3]) << 16);
        unsigned int Cu = (unsigned)f2bf(p[8 * g + 4]) | ((unsigned)f2bf(p[8 * g + 5]) << 16);
        unsigned int Du = (unsigned)f2bf(p[8 * g + 6]) | ((unsigned)f2bf(p[8 * g + 7]) << 16);
        int s0 = (lg & 1) * 2;
        int src0 = lr + 16 * s0, src1 = src0 + 16;
        bool hi = lg >= 2;
        int a0 = __shfl((int)Au, src0), c0 = __shfl((int)Cu, src0);
        int b0 = __shfl((int)Bu, src0), d0 = __shfl((int)Du, src0);
        int a1 = __shfl((int)Au, src1), c1 = __shfl((int)Cu, src1);
        int b1 = __shfl((int)Bu, src1), d1 = __shfl((int)Du, src1);
        bfrag[g][0] = hi ? (unsigned)c0 : (unsigned)a0;
        bfrag[g][1] = hi ? (unsigned)d0 : (unsigned)b0;
        bfrag[g][2] = hi ? (unsigned)c1 : (unsigned)a1;
        bfrag[g][3] = hi ? (unsigned)d1 : (unsigned)b1;
      }

      // ---- O^T += V^T · P^T
      __builtin_amdgcn_s_setprio(1);
#pragma unroll
      for (int g = 0; g < 2; ++g)
#pragma unroll
        for (int dt = 0; dt < 8; ++dt) {
          int d = dt * 16 + lr;
          int elem = d * 64 + (((4 * g + lg) ^ (lr & 7)) * 8);
          bf16x8 vf = *reinterpret_cast<const bf16x8*>(&sV[cur][elem]);
          ao[dt] = __builtin_amdgcn_mfma_f32_16x16x32_bf16(
              vf, *reinterpret_cast<const bf16x8*>(&bfrag[g]), ao[dt], 0, 0, 0);
        }
      __builtin_amdgcn_s_setprio(0);
    }

    __syncthreads();
    cur ^= 1;
  }

  // epilogue: divide by l, store bf16 (lane q=lr, d = dt*16+lg*4+r -> 8B stores)
  float inv = 1.0f / lrun;
  int qrow = qw + lr;
#pragma unroll
  for (int dt = 0; dt < 8; ++dt) {
    u16x4 o4;
#pragma unroll
    for (int r = 0; r < 4; ++r) o4[r] = f2bf(ao[dt][r] * inv);
    *reinterpret_cast<u16x4*>(&O[(size_t)qrow * HID + h * HD + dt * 16 + lg * 4]) = o4;
  }
}

// ---------------- launch ----------------
extern "C" void kernel_launch(void* const* d_in, const int* in_sizes, int n_in,
                              void* d_out, int out_size, void* d_ws, size_t ws_size,
                              hipStream_t stream) {
  const float* hs = (const float*)d_in[0];
  // d_in[1] = position_ids (arange, unused: positions derived from row index)
  const float* Wq = (const float*)d_in[2];
  const float* Wk = (const float*)d_in[3];
  const float* Wv = (const float*)d_in[4];
  const float* Wo = (const float*)d_in[5];

  unsigned short* ws = (unsigned short*)d_ws;
  size_t off = 0;
  unsigned short* H16  = ws + off; off += (size_t)S_LEN * HID;     // also attn-out
  unsigned short* Wcat = ws + off; off += (size_t)NQKV * HID;      // Wq|Wk|Wv, later Wo in rows 0..4095
  unsigned short* Qb   = ws + off; off += (size_t)S_LEN * HID;
  unsigned short* Kb   = ws + off; off += (size_t)S_LEN * NKV * HD;
  unsigned short* Vt   = ws + off; off += (size_t)S_LEN * NKV * HD;
  float2* tab = (float2*)(ws + off); off += (size_t)S_LEN * 64 * 2 * 2;

  auto cast = [&](const float* src, unsigned short* dst, size_t n) {
    int n4 = (int)(n / 4);
    cast_f32_bf16<<<(n4 + 255) / 256, 256, 0, stream>>>(src, dst, n4);
  };

  rope_table<<<(S_LEN * 64 + 255) / 256, 256, 0, stream>>>(tab);
  cast(hs, H16, (size_t)S_LEN * HID);
  cast(Wq, Wcat, (size_t)HID * HID);
  cast(Wk, Wcat + (size_t)HID * HID, (size_t)NKV * HD * HID);
  cast(Wv, Wcat + (size_t)(HID + NKV * HD) * HID, (size_t)NKV * HD * HID);

  // fused QKV projection (V written transposed)
  gemm_qkv<<<dim3(NQKV / 128, S_LEN / 128), 256, 0, stream>>>(
      H16, Wcat, Qb, Kb, Vt);

  // Wo cast reuses Wcat rows 0..4095 (stream-ordered after QKV GEMM)
  cast(Wo, Wcat, (size_t)HID * HID);

  // RoPE on Q and K
  {
    int totq = S_LEN * NH * 64;
    rope_kernel<<<(totq + 255) / 256, 256, 0, stream>>>(Qb, tab, NH, totq);
    int totk = S_LEN * NKV * 64;
    rope_kernel<<<(totk + 255) / 256, 256, 0, stream>>>(Kb, tab, NKV, totk);
  }

  // attention -> H16
  attn_kernel<<<dim3(S_LEN / 128, NH), 512, 0, stream>>>(Qb, Kb, Vt, H16);

  // output projection -> fp32 d_out
  gemm_bt<<<dim3(HID / 128, S_LEN / 128), 256, 0, stream>>>(
      H16, Wcat, (float*)d_out, S_LEN, HID, HID);
}

// Round 4
// 403.738 us; speedup vs baseline: 2.2410x; 1.0082x over previous
//
#include <hip/hip_runtime.h>

typedef __attribute__((ext_vector_type(4))) float f32x4;
typedef __attribute__((ext_vector_type(8))) __bf16 bf16x8;
typedef __attribute__((ext_vector_type(4))) unsigned short u16x4;

#define DEVI static __device__ __forceinline__
#define AS1 __attribute__((address_space(1)))
#define AS3 __attribute__((address_space(3)))

static constexpr int S_LEN = 2048;
static constexpr int HID   = 4096;
static constexpr int NH    = 32;
static constexpr int NKV   = 8;
static constexpr int HD    = 128;
static constexpr int NQKV  = HID + 2 * NKV * HD;   // 6144

DEVI unsigned short f2bf(float f) {
  unsigned int u = __float_as_uint(f);
  u += 0x7FFFu + ((u >> 16) & 1u);
  return (unsigned short)(u >> 16);
}
DEVI float bf2f(unsigned short h) {
  return __uint_as_float(((unsigned int)h) << 16);
}

// ---------------- fp32 -> bf16 cast (float4 vectorized) ----------------
__global__ void cast_f32_bf16(const float* __restrict__ in,
                              unsigned short* __restrict__ out, int n4) {
  int i = blockIdx.x * 256 + threadIdx.x;
  if (i >= n4) return;
  float4 v = reinterpret_cast<const float4*>(in)[i];
  u16x4 o;
  o[0] = f2bf(v.x); o[1] = f2bf(v.y); o[2] = f2bf(v.z); o[3] = f2bf(v.w);
  reinterpret_cast<u16x4*>(out)[i] = o;
}

// ---------------- RoPE cos/sin table [S][64] float2 ----------------
__global__ void rope_table(float2* __restrict__ tab) {
  int i = blockIdx.x * 256 + threadIdx.x;
  if (i >= S_LEN * 64) return;
  int j = i & 63, s = i >> 6;
  float inv = powf(10000.0f, -(float)j / 64.0f);
  float ang = (float)s * inv;
  tab[i] = make_float2(cosf(ang), sinf(ang));
}

// ---------------- RoPE in place on bf16 [S][Hn*128] ----------------
__global__ void rope_kernel(unsigned short* __restrict__ X,
                            const float2* __restrict__ tab, int Hn, int total) {
  int i = blockIdx.x * 256 + threadIdx.x;
  if (i >= total) return;
  int j = i & 63;              // freq index 0..63
  int h = (i >> 6) % Hn;
  int s = i / (64 * Hn);
  float2 cs = tab[s * 64 + j];
  unsigned short* p = X + (size_t)s * Hn * HD + h * HD;
  float x1 = bf2f(p[j]);
  float x2 = bf2f(p[j + 64]);
  p[j]      = f2bf(x1 * cs.x - x2 * cs.y);
  p[j + 64] = f2bf(x2 * cs.x + x1 * cs.y);
}

// ============ fused QKV GEMM, 256x256 tile, BK=64, 8-wave, 8-phase ============
// C[2048 x 6144] = H @ Wcat^T. Epilogue routes by block col: Q / K / V^T.
//
// LDS per buffer (64 KB, 2 buffers = 128 KB):
//   A: [256 rows][64 k] as 4 stage-bands of 64 rows; chunk swizzle c^=(row&7)
//   B: [kh=2][256 n][32 k]; chunk swizzle c^=((n>>1)&3)
// Stage unit = 8 KB = one global_load_lds per thread (512 thr x 16 B); LDS dest
// is linear per wave (base + lane*16B), swizzle applied on the GLOBAL src addr.
//
// Phase p computes (buf, mh, kh); per phase: vmcnt(4); 8x ds_read_b128;
// 2 stage units; s_barrier; lgkmcnt(0)+sched_barrier; 16 MFMA (setprio 1);
// s_barrier.  Stage placement (iteration computes t=2i from buf0 @P1-4,
// t+1 from buf1 @P5-8); every unit: stage -> first-read distance >= 4 phases
// (so per-phase vmcnt(4) == 2 phases' loads outstanding guarantees landing),
// and stage phase > last reader phase of the region's old tile:
//   P1: B(buf1,kh0,t+1)  [old read <=prev-P7; first read P5, d=4]
//   P2: B(buf1,kh1,t+1)  [<=prev-P8; read P6, d=4]
//   P3: A(buf1,bands 1&3,t+1) [<=prev-P8; read P7, d=4]
//   P4: B(buf0,kh0,t+2)  [<=P3; read next-P1, d=5]
//   P5: A(buf0,bands 0&2,t+2) [<=P2; read next-P1, d=4]
//   P6: B(buf0,kh1,t+2)  [<=P4; read next-P2, d=4]
//   P7: A(buf0,bands 1&3,t+2) [<=P4; read next-P3, d=4]
//   P8: A(buf1,bands 0&2,t+3) [<=P6; read next-P5, d=5]
// i==0: P1-P3 skipped (prologue staged tiles 0,1); i==last: P4-P8 skipped.
__global__ __launch_bounds__(512, 2) void gemm_qkv256(
    const unsigned short* __restrict__ A,   // [2048][4096]
    const unsigned short* __restrict__ B,   // [6144][4096]
    unsigned short* __restrict__ Qb,
    unsigned short* __restrict__ Kb,
    unsigned short* __restrict__ Vt) {
  __shared__ __align__(16) unsigned short lds[2][32768];
  const int tid = threadIdx.x;
  const int lane = tid & 63, w = tid >> 6;
  const int wm = w >> 2, wn = w & 3;
  const int lr = lane & 15, lg = lane >> 4;
  const int bx = blockIdx.x, by = blockIdx.y;
  const int m0 = by * 256, n0 = bx * 256;
  const int Kd = HID;

  const int sAr = tid >> 3, sAp = tid & 7;   // A stage: row-in-band, phys chunk
  const int sBn = tid >> 2, sBp = tid & 3;   // B stage: row-in-half, phys chunk
  auto stageA = [&](int buf, int t, int band) {
    int row = band * 64 + sAr;
    __builtin_amdgcn_global_load_lds(
        (const AS1 void*)(A + (size_t)(m0 + row) * Kd + t * 64 + ((sAp ^ (row & 7)) * 8)),
        (AS3 void*)(&lds[buf][row * 64 + sAp * 8]), 16, 0, 0);
  };
  auto stageB = [&](int buf, int t, int kh, int hb) {
    int n = hb * 128 + sBn;
    __builtin_amdgcn_global_load_lds(
        (const AS1 void*)(B + (size_t)(n0 + n) * Kd + t * 64 + kh * 32 + ((sBp ^ ((n >> 1) & 3)) * 8)),
        (AS3 void*)(&lds[buf][16384 + kh * 8192 + n * 32 + sBp * 8]), 16, 0, 0);
  };

  // ds_read element offsets (row&7 == lr&7, (n>>1)&3 == (lr>>1)&3)
  const int aoff0 = (wm * 128 + lr) * 64 + ((lg ^ (lr & 7)) * 8);        // kh=0
  const int aoff1 = (wm * 128 + lr) * 64 + (((4 + lg) ^ (lr & 7)) * 8);  // kh=1
  const int boff  = 16384 + (wn * 64 + lr) * 32 + ((lg ^ ((lr >> 1) & 3)) * 8);

  f32x4 acc[8][4] = {};

  // prologue: fully stage tiles 0 (buf0) and 1 (buf1)
#pragma unroll
  for (int b = 0; b < 4; ++b) { stageA(0, 0, b); stageA(1, 1, b); }
#pragma unroll
  for (int kh = 0; kh < 2; ++kh)
#pragma unroll
    for (int hb = 0; hb < 2; ++hb) { stageB(0, 0, kh, hb); stageB(1, 1, kh, hb); }
  asm volatile("s_waitcnt vmcnt(0)" ::: "memory");
  __builtin_amdgcn_s_barrier();

#define PHASE(BUF, MH, KH, ...)                                                \
  do {                                                                         \
    asm volatile("s_waitcnt vmcnt(4)" ::: "memory");                           \
    const unsigned short* ab = &lds[BUF][((KH) ? aoff1 : aoff0) + (MH) * 4096];\
    bf16x8 af0 = *reinterpret_cast<const bf16x8*>(ab);                         \
    bf16x8 af1 = *reinterpret_cast<const bf16x8*>(ab + 1024);                  \
    bf16x8 af2 = *reinterpret_cast<const bf16x8*>(ab + 2048);                  \
    bf16x8 af3 = *reinterpret_cast<const bf16x8*>(ab + 3072);                  \
    const unsigned short* bb = &lds[BUF][boff + (KH) * 8192];                  \
    bf16x8 bg0 = *reinterpret_cast<const bf16x8*>(bb);                         \
    bf16x8 bg1 = *reinterpret_cast<const bf16x8*>(bb + 512);                   \
    bf16x8 bg2 = *reinterpret_cast<const bf16x8*>(bb + 1024);                  \
    bf16x8 bg3 = *reinterpret_cast<const bf16x8*>(bb + 1536);                  \
    __VA_ARGS__                                                                \
    __builtin_amdgcn_s_barrier();                                              \
    asm volatile("s_waitcnt lgkmcnt(0)" ::: "memory");                         \
    __builtin_amdgcn_sched_barrier(0);                                         \
    __builtin_amdgcn_s_setprio(1);                                             \
    acc[(MH)*4+0][0] = __builtin_amdgcn_mfma_f32_16x16x32_bf16(af0, bg0, acc[(MH)*4+0][0],0,0,0); \
    acc[(MH)*4+0][1] = __builtin_amdgcn_mfma_f32_16x16x32_bf16(af0, bg1, acc[(MH)*4+0][1],0,0,0); \
    acc[(MH)*4+0][2] = __builtin_amdgcn_mfma_f32_16x16x32_bf16(af0, bg2, acc[(MH)*4+0][2],0,0,0); \
    acc[(MH)*4+0][3] = __builtin_amdgcn_mfma_f32_16x16x32_bf16(af0, bg3, acc[(MH)*4+0][3],0,0,0); \
    acc[(MH)*4+1][0] = __builtin_amdgcn_mfma_f32_16x16x32_bf16(af1, bg0, acc[(MH)*4+1][0],0,0,0); \
    acc[(MH)*4+1][1] = __builtin_amdgcn_mfma_f32_16x16x32_bf16(af1, bg1, acc[(MH)*4+1][1],0,0,0); \
    acc[(MH)*4+1][2] = __builtin_amdgcn_mfma_f32_16x16x32_bf16(af1, bg2, acc[(MH)*4+1][2],0,0,0); \
    acc[(MH)*4+1][3] = __builtin_amdgcn_mfma_f32_16x16x32_bf16(af1, bg3, acc[(MH)*4+1][3],0,0,0); \
    acc[(MH)*4+2][0] = __builtin_amdgcn_mfma_f32_16x16x32_bf16(af2, bg0, acc[(MH)*4+2][0],0,0,0); \
    acc[(MH)*4+2][1] = __builtin_amdgcn_mfma_f32_16x16x32_bf16(af2, bg1, acc[(MH)*4+2][1],0,0,0); \
    acc[(MH)*4+2][2] = __builtin_amdgcn_mfma_f32_16x16x32_bf16(af2, bg2, acc[(MH)*4+2][2],0,0,0); \
    acc[(MH)*4+2][3] = __builtin_amdgcn_mfma_f32_16x16x32_bf16(af2, bg3, acc[(MH)*4+2][3],0,0,0); \
    acc[(MH)*4+3][0] = __builtin_amdgcn_mfma_f32_16x16x32_bf16(af3, bg0, acc[(MH)*4+3][0],0,0,0); \
    acc[(MH)*4+3][1] = __builtin_amdgcn_mfma_f32_16x16x32_bf16(af3, bg1, acc[(MH)*4+3][1],0,0,0); \
    acc[(MH)*4+3][2] = __builtin_amdgcn_mfma_f32_16x16x32_bf16(af3, bg2, acc[(MH)*4+3][2],0,0,0); \
    acc[(MH)*4+3][3] = __builtin_amdgcn_mfma_f32_16x16x32_bf16(af3, bg3, acc[(MH)*4+3][3],0,0,0); \
    __builtin_amdgcn_s_setprio(0);                                             \
    __builtin_amdgcn_s_barrier();                                              \
  } while (0)

  for (int i = 0; i < 32; ++i) {
    const int t = 2 * i;
    const bool nf = (i != 0), nl = (i != 31);
    PHASE(0, 0, 0, if (nf) { stageB(1, t + 1, 0, 0); stageB(1, t + 1, 0, 1); });
    PHASE(0, 0, 1, if (nf) { stageB(1, t + 1, 1, 0); stageB(1, t + 1, 1, 1); });
    PHASE(0, 1, 0, if (nf) { stageA(1, t + 1, 1); stageA(1, t + 1, 3); });
    PHASE(0, 1, 1, if (nl) { stageB(0, t + 2, 0, 0); stageB(0, t + 2, 0, 1); });
    PHASE(1, 0, 0, if (nl) { stageA(0, t + 2, 0); stageA(0, t + 2, 2); });
    PHASE(1, 0, 1, if (nl) { stageB(0, t + 2, 1, 0); stageB(0, t + 2, 1, 1); });
    PHASE(1, 1, 0, if (nl) { stageA(0, t + 2, 1); stageA(0, t + 2, 3); });
    PHASE(1, 1, 1, if (nl) { stageA(1, t + 3, 0); stageA(1, t + 3, 2); });
  }
#undef PHASE

  // epilogue: route by block col region (bx<16: Q, <20: K, else V transposed)
#pragma unroll
  for (int ar = 0; ar < 8; ++ar) {
#pragma unroll
    for (int fc = 0; fc < 4; ++fc) {
      const int gcol = n0 + wn * 64 + fc * 16 + lr;
      const int growb = m0 + wm * 128 + (ar >> 2) * 64 + (ar & 3) * 16 + lg * 4;
      if (bx < 16) {
#pragma unroll
        for (int rr = 0; rr < 4; ++rr)
          Qb[(size_t)(growb + rr) * HID + gcol] = f2bf(acc[ar][fc][rr]);
      } else if (bx < 20) {
#pragma unroll
        for (int rr = 0; rr < 4; ++rr)
          Kb[(size_t)(growb + rr) * (NKV * HD) + (gcol - HID)] = f2bf(acc[ar][fc][rr]);
      } else {
        u16x4 o4;
#pragma unroll
        for (int rr = 0; rr < 4; ++rr) o4[rr] = f2bf(acc[ar][fc][rr]);
        *reinterpret_cast<u16x4*>(
            &Vt[(size_t)(gcol - HID - NKV * HD) * S_LEN + growb]) = o4;
      }
    }
  }
}

// ---------------- bf16 GEMM: C = A @ B^T (O-projection, fp32 out, m97) ----------------
__global__ __launch_bounds__(256) void gemm_bt(
    const unsigned short* __restrict__ A,
    const unsigned short* __restrict__ B,
    float* __restrict__ C, int M, int N, int Kd) {
  __shared__ __align__(16) unsigned short sA[128 * 32];
  __shared__ __align__(16) unsigned short sB[128 * 32];
  const int tid = threadIdx.x;
  const int lane = tid & 63, w = tid >> 6;
  const int wr = w >> 1, wc = w & 1;
  const int lr = lane & 15, lg = lane >> 4;
  const int m0 = blockIdx.y * 128, n0 = blockIdx.x * 128;

  f32x4 acc[4][4] = {};

  for (int k0 = 0; k0 < Kd; k0 += 32) {
#pragma unroll
    for (int r = 0; r < 2; ++r) {
      int e = (tid + r * 256) * 8;
      int row = e >> 5, col = e & 31;
      __builtin_amdgcn_global_load_lds(
          (const AS1 void*)(A + (size_t)(m0 + row) * Kd + k0 + col),
          (AS3 void*)(sA + e), 16, 0, 0);
      __builtin_amdgcn_global_load_lds(
          (const AS1 void*)(B + (size_t)(n0 + row) * Kd + k0 + col),
          (AS3 void*)(sB + e), 16, 0, 0);
    }
    __syncthreads();

    bf16x8 af[4], bfr[4];
#pragma unroll
    for (int m = 0; m < 4; ++m)
      af[m] = *reinterpret_cast<const bf16x8*>(&sA[(wr * 64 + m * 16 + lr) * 32 + lg * 8]);
#pragma unroll
    for (int n = 0; n < 4; ++n)
      bfr[n] = *reinterpret_cast<const bf16x8*>(&sB[(wc * 64 + n * 16 + lr) * 32 + lg * 8]);
#pragma unroll
    for (int m = 0; m < 4; ++m)
#pragma unroll
      for (int n = 0; n < 4; ++n)
        acc[m][n] = __builtin_amdgcn_mfma_f32_16x16x32_bf16(af[m], bfr[n], acc[m][n], 0, 0, 0);
    __syncthreads();
  }

#pragma unroll
  for (int m = 0; m < 4; ++m)
#pragma unroll
    for (int n = 0; n < 4; ++n) {
      int gcol = n0 + wc * 64 + n * 16 + lr;
#pragma unroll
      for (int r = 0; r < 4; ++r) {
        int grow = m0 + wr * 64 + m * 16 + lg * 4 + r;
        C[(size_t)grow * N + gcol] = acc[m][n][r];
      }
    }
}

// ---------------- causal GQA flash attention, swapped-QK^T, 8-wave ----------------
__global__ __launch_bounds__(512, 4) void attn_kernel(
    const unsigned short* __restrict__ Q,   // [S][NH*HD]
    const unsigned short* __restrict__ Kb,  // [S][NKV*HD]
    const unsigned short* __restrict__ Vt,  // [NKV*HD][S]
    unsigned short* __restrict__ O) {       // [S][NH*HD]
  __shared__ __align__(16) unsigned short sK[2][64 * 128];
  __shared__ __align__(16) unsigned short sV[2][128 * 64];
  const int tid = threadIdx.x;
  const int lane = tid & 63, w = tid >> 6;
  const int lr = lane & 15, lg = lane >> 4;
  const int qt = (int)gridDim.x - 1 - (int)blockIdx.x;  // descending work order
  const int h = blockIdx.y, kvh = h >> 2;
  const int q0 = qt * 128, qw = q0 + w * 16;
  const int KVS = NKV * HD;

  bf16x8 qf[4];
#pragma unroll
  for (int ks = 0; ks < 4; ++ks)
    qf[ks] = *reinterpret_cast<const bf16x8*>(
        &Q[(size_t)(qw + lr) * HID + h * HD + ks * 32 + lg * 8]);

  f32x4 ao[8] = {};
  float mrun = -INFINITY, lrun = 0.f;
  const float scale = 0.08838834764831845f;  // 1/sqrt(128)
  const int ntiles = 2 * qt + 2;

  auto stage = [&](int b, int kv0) {
#pragma unroll
    for (int i = 0; i < 2; ++i) {
      int off = (tid + i * 512) * 8;
      int r = off >> 7, c = (off >> 3) & 15;
      __builtin_amdgcn_global_load_lds(
          (const AS1 void*)(Kb + (size_t)(kv0 + r) * KVS + kvh * HD + ((c ^ (r & 7)) * 8)),
          (AS3 void*)(&sK[b][off]), 16, 0, 0);
    }
#pragma unroll
    for (int i = 0; i < 2; ++i) {
      int off = (tid + i * 512) * 8;
      int r = off >> 6, c = (off >> 3) & 7;
      __builtin_amdgcn_global_load_lds(
          (const AS1 void*)(Vt + (size_t)(kvh * HD + r) * S_LEN + kv0 + ((c ^ (r & 7)) * 8)),
          (AS3 void*)(&sV[b][off]), 16, 0, 0);
    }
  };

  stage(0, 0);
  __syncthreads();
  int cur = 0;

  for (int t = 0; t < ntiles; ++t) {
    const int kv0 = t * 64;
    if (t + 1 < ntiles) stage(cur ^ 1, kv0 + 64);

    if (kv0 <= qw + 15) {
      f32x4 sacc[4] = {};
      __builtin_amdgcn_s_setprio(1);
#pragma unroll
      for (int kt = 0; kt < 4; ++kt)
#pragma unroll
        for (int ks = 0; ks < 4; ++ks) {
          int elem = (kt * 16 + lr) * 128 + (((4 * ks + lg) ^ (lr & 7)) * 8);
          bf16x8 kf = *reinterpret_cast<const bf16x8*>(&sK[cur][elem]);
          sacc[kt] = __builtin_amdgcn_mfma_f32_16x16x32_bf16(kf, qf[ks], sacc[kt], 0, 0, 0);
        }
      __builtin_amdgcn_s_setprio(0);

      const bool needMask = (kv0 + 63 > qw);
      const int qg = qw + lr;
      float p[16];
      float tmax = -INFINITY;
#pragma unroll
      for (int kt = 0; kt < 4; ++kt)
#pragma unroll
        for (int r = 0; r < 4; ++r) {
          float v = sacc[kt][r] * scale;
          if (needMask && (kv0 + kt * 16 + lg * 4 + r > qg)) v = -INFINITY;
          p[kt * 4 + r] = v;
          tmax = fmaxf(tmax, v);
        }
      tmax = fmaxf(tmax, __shfl_xor(tmax, 16));
      tmax = fmaxf(tmax, __shfl_xor(tmax, 32));
      float mnew = fmaxf(mrun, tmax);
      float corr = __expf(mrun - mnew);
      mrun = mnew;
      float rs = 0.f;
#pragma unroll
      for (int i = 0; i < 16; ++i) { p[i] = __expf(p[i] - mnew); rs += p[i]; }
      rs += __shfl_xor(rs, 16);
      rs += __shfl_xor(rs, 32);
      lrun = lrun * corr + rs;
#pragma unroll
      for (int dt = 0; dt < 8; ++dt) ao[dt] *= corr;

      unsigned int bfrag[2][4];
#pragma unroll
      for (int g = 0; g < 2; ++g) {
        unsigned int Au = (unsigned)f2bf(p[8 * g + 0]) | ((unsigned)f2bf(p[8 * g + 1]) << 16);
        unsigned int Bu = (unsigned)f2bf(p[8 * g + 2]) | ((unsigned)f2bf(p[8 * g + 3]) << 16);
        unsigned int Cu = (unsigned)f2bf(p[8 * g + 4]) | ((unsigned)f2bf(p[8 * g + 5]) << 16);
        unsigned int Du = (unsigned)f2bf(p[8 * g + 6]) | ((unsigned)f2bf(p[8 * g + 7]) << 16);
        int s0 = (lg & 1) * 2;
        int src0 = lr + 16 * s0, src1 = src0 + 16;
        bool hi = lg >= 2;
        int a0 = __shfl((int)Au, src0), c0 = __shfl((int)Cu, src0);
        int b0 = __shfl((int)Bu, src0), d0 = __shfl((int)Du, src0);
        int a1 = __shfl((int)Au, src1), c1 = __shfl((int)Cu, src1);
        int b1 = __shfl((int)Bu, src1), d1 = __shfl((int)Du, src1);
        bfrag[g][0] = hi ? (unsigned)c0 : (unsigned)a0;
        bfrag[g][1] = hi ? (unsigned)d0 : (unsigned)b0;
        bfrag[g][2] = hi ? (unsigned)c1 : (unsigned)a1;
        bfrag[g][3] = hi ? (unsigned)d1 : (unsigned)b1;
      }

      __builtin_amdgcn_s_setprio(1);
#pragma unroll
      for (int g = 0; g < 2; ++g)
#pragma unroll
        for (int dt = 0; dt < 8; ++dt) {
          int d = dt * 16 + lr;
          int elem = d * 64 + (((4 * g + lg) ^ (lr & 7)) * 8);
          bf16x8 vf = *reinterpret_cast<const bf16x8*>(&sV[cur][elem]);
          ao[dt] = __builtin_amdgcn_mfma_f32_16x16x32_bf16(
              vf, *reinterpret_cast<const bf16x8*>(&bfrag[g]), ao[dt], 0, 0, 0);
        }
      __builtin_amdgcn_s_setprio(0);
    }

    __syncthreads();
    cur ^= 1;
  }

  float inv = 1.0f / lrun;
  int qrow = qw + lr;
#pragma unroll
  for (int dt = 0; dt < 8; ++dt) {
    u16x4 o4;
#pragma unroll
    for (int r = 0; r < 4; ++r) o4[r] = f2bf(ao[dt][r] * inv);
    *reinterpret_cast<u16x4*>(&O[(size_t)qrow * HID + h * HD + dt * 16 + lg * 4]) = o4;
  }
}

// ---------------- launch ----------------
extern "C" void kernel_launch(void* const* d_in, const int* in_sizes, int n_in,
                              void* d_out, int out_size, void* d_ws, size_t ws_size,
                              hipStream_t stream) {
  const float* hs = (const float*)d_in[0];
  // d_in[1] = position_ids (arange, unused: positions derived from row index)
  const float* Wq = (const float*)d_in[2];
  const float* Wk = (const float*)d_in[3];
  const float* Wv = (const float*)d_in[4];
  const float* Wo = (const float*)d_in[5];

  unsigned short* ws = (unsigned short*)d_ws;
  size_t off = 0;
  unsigned short* H16  = ws + off; off += (size_t)S_LEN * HID;     // also attn-out
  unsigned short* Wcat = ws + off; off += (size_t)NQKV * HID;      // Wq|Wk|Wv, later Wo in rows 0..4095
  unsigned short* Qb   = ws + off; off += (size_t)S_LEN * HID;
  unsigned short* Kb   = ws + off; off += (size_t)S_LEN * NKV * HD;
  unsigned short* Vt   = ws + off; off += (size_t)S_LEN * NKV * HD;
  float2* tab = (float2*)(ws + off); off += (size_t)S_LEN * 64 * 2 * 2;

  auto cast = [&](const float* src, unsigned short* dst, size_t n) {
    int n4 = (int)(n / 4);
    cast_f32_bf16<<<(n4 + 255) / 256, 256, 0, stream>>>(src, dst, n4);
  };

  rope_table<<<(S_LEN * 64 + 255) / 256, 256, 0, stream>>>(tab);
  cast(hs, H16, (size_t)S_LEN * HID);
  cast(Wq, Wcat, (size_t)HID * HID);
  cast(Wk, Wcat + (size_t)HID * HID, (size_t)NKV * HD * HID);
  cast(Wv, Wcat + (size_t)(HID + NKV * HD) * HID, (size_t)NKV * HD * HID);

  // fused QKV projection, 256^2 8-phase (V written transposed)
  gemm_qkv256<<<dim3(NQKV / 256, S_LEN / 256), 512, 0, stream>>>(
      H16, Wcat, Qb, Kb, Vt);

  // Wo cast reuses Wcat rows 0..4095 (stream-ordered after QKV GEMM)
  cast(Wo, Wcat, (size_t)HID * HID);

  // RoPE on Q and K
  {
    int totq = S_LEN * NH * 64;
    rope_kernel<<<(totq + 255) / 256, 256, 0, stream>>>(Qb, tab, NH, totq);
    int totk = S_LEN * NKV * 64;
    rope_kernel<<<(totk + 255) / 256, 256, 0, stream>>>(Kb, tab, NKV, totk);
  }

  // attention -> H16
  attn_kernel<<<dim3(S_LEN / 128, NH), 512, 0, stream>>>(Qb, Kb, Vt, H16);

  // output projection -> fp32 d_out
  gemm_bt<<<dim3(HID / 128, S_LEN / 128), 256, 0, stream>>>(
      H16, Wcat, (float*)d_out, S_LEN, HID, HID);
}